// Round 16
// baseline (74.295 us; speedup 1.0000x reference)
//
#include <hip/hip_runtime.h>
#include <hip/hip_bf16.h>
#include <math.h>

// B=16, S=8192, D=256. out[b,s,d] = y[b,s]*W[d] + bias[d],
// y = lowpass(x) keep |f|<2048, x = ids/255.
// Parity split: y[2i]   = 0.5*x_e[i] + sum_j Kp[j]*x_o[(i-1-j) mod 4096]
//               y[2i+1] = 0.5*x_o[i] + sum_j Kp[j]*x_e[(i-j)   mod 4096]
// Kp[j] = (-1)^j * cot(pi*(2j+1)/8192)/8192.
// conv_kernel (512 blocks): MFMA FIR -> ys[b][s] (512 KB ws, L2-resident).
// write_kernel v2 (2048 blocks, grid-stride sweep, PURE-STORE): all 16 ys
// values preloaded to registers (static-index unroll), then 16 nt stores with
// no interleaved loads. LAUNCHED TWICE (idempotent) as a duration probe:
// write dur = (total - (prep+conv+gaps)) / 2.

#define SEQ    8192
#define HSEQ   4096
#define DIM    256
#define NBAT   16
#define RROW   8224                     // unrolled circular reversed row (shorts)
#define APN    (128*512)                // Apack shorts: 128 j-blocks x 64 lanes x 8
#define AP_OFF 0
#define RO_OFF (APN*2)                  // 131072 B
#define RE_OFF (RO_OFF + NBAT*RROW*2)   // 394240 B
#define YS_OFF (RE_OFF + NBAT*RROW*2)   // 657408 B; ys = 16*8192 f32 = 512 KB

typedef __attribute__((ext_vector_type(8))) short short8v;
typedef __attribute__((ext_vector_type(4))) float f32x4;

__device__ __forceinline__ short bfbits(float f) {
    __hip_bfloat16 h = __float2bfloat16(f);
    return *(short*)&h;
}

__global__ __launch_bounds__(256)
void prep_kernel(const int* __restrict__ ids, unsigned char* __restrict__ ws8) {
    short* Ap = (short*)(ws8 + AP_OFF);
    short* Ro = (short*)(ws8 + RO_OFF);
    short* Re = (short*)(ws8 + RE_OFF);
    const int idx = blockIdx.x * 256 + threadIdx.x;
    const int n   = gridDim.x * 256;

    // A fragments in lane order: Ap[jb*512 + l*8 + e] = Ktil[(32jb + oc + 8koff + e) mod 4096]
    for (int i = idx; i < APN; i += n) {
        int jb = i >> 9, r = i & 511, l = r >> 3, e = r & 7;
        int oc = l & 15, koff = l >> 4;
        int j = (32 * jb + oc + 8 * koff + e) & (HSEQ - 1);
        double ang = M_PI * (2.0 * j + 1.0) / 8192.0;
        double v = (cos(ang) / sin(ang)) / (8192.0 * 255.0);
        if (j & 1) v = -v;
        Ap[i] = bfbits((float)v);
    }
    // Reversed parity rows (raw id units, exact bf16), periodic unrolled:
    //  Ro[b][u] = ids[b][2*((4095-u)&4095)+1], Re[b][u] = ids[b][2*((4096-u)&4095)]
    for (int i = idx; i < NBAT * RROW; i += n) {
        int b = i / RROW, u = i - b * RROW;
        const int* row = ids + b * SEQ;
        int mo = (4095 - u) & (HSEQ - 1);
        int me = (4096 - u) & (HSEQ - 1);
        Ro[i] = bfbits((float)row[2 * mo + 1]);
        Re[i] = bfbits((float)row[2 * me]);
    }
}

__global__ __launch_bounds__(256)
void conv_kernel(const int* __restrict__ ids,
                 unsigned char* __restrict__ ws8) {
    __shared__ f32x4 red[4][64];

    const int bid = blockIdx.x;
    const int chunk = bid & 31;          // 32 chunks of 256 samples per row
    const int b  = bid >> 5;
    const int s0 = chunk << 8;
    const int i0 = s0 >> 1;              // packed-output base per parity
    const int t = threadIdx.x, w = t >> 6, l = t & 63;
    const int oc = l & 15, koff = l >> 4;
    const int P = oc >> 3, g = oc & 7;   // column = (parity, group)

    // A: contiguous 1KB per wave per iter (pre-packed lane order)
    const short* Apw = (const short*)(ws8 + AP_OFF) + ((w * 32) << 9) + l * 8;
    // B: one Rev row per lane; same base offset for both parities
    const short* Rp = (const short*)(ws8 + (P ? RE_OFF : RO_OFF)) + b * RROW
                      + (HSEQ - i0 - 16 * g) + 8 * koff + (w << 10);

    f32x4 acc = {0.f, 0.f, 0.f, 0.f};
    #pragma unroll 4
    for (int c = 0; c < 32; ++c) {
        short8v a  = *(const short8v*)(Apw + (c << 9));
        short8v bv = *(const short8v*)(Rp + (c << 5));
        acc = __builtin_amdgcn_mfma_f32_16x16x32_bf16(a, bv, acc, 0, 0, 0);
    }
    red[w][l] = acc;
    __syncthreads();

    // One output per thread. C layout (m89): col = lane&15, row = (lane>>4)*4+q.
    // Value C[o][g2] -> local s = 2*(16*(g2&7) + o) + (g2>>3).
    {
        const int g2 = t >> 4, o = t & 15;
        float s = 0.f;
        #pragma unroll
        for (int k = 0; k < 4; ++k) s += red[k][(o >> 2) * 16 + g2][o & 3];
        const int ls = 2 * (16 * (g2 & 7) + o) + (g2 >> 3);
        s += (float)ids[b * SEQ + s0 + ls] * (0.5f / 255.0f);
        ((float*)(ws8 + YS_OFF))[b * SEQ + s0 + ls] = s;
    }
}

__global__ __launch_bounds__(256)
void write_kernel(const unsigned char* __restrict__ ws8,
                  const float* __restrict__ W,
                  const float* __restrict__ bias,
                  float* __restrict__ out) {
    const float* ys = (const float*)(ws8 + YS_OFF);
    const int t = threadIdx.x;
    const int d = (t & 63) << 2;               // idx%64 == t%64 (stride mult of 64)
    const float4 w4 = *(const float4*)(W + d);
    const float4 b4 = *(const float4*)(bias + d);

    const int base   = blockIdx.x * 256 + t;   // float4 index
    const int stride = 2048 * 256;             // 16 iterations cover 8,388,608

    // Phase 1: preload all 16 y values (static indices -> registers).
    float y[16];
    #pragma unroll 16
    for (int k = 0; k < 16; ++k) y[k] = ys[(base + k * stride) >> 6];

    // Phase 2: pure store stream, no interleaved loads.
    f32x4* o = (f32x4*)out;
    #pragma unroll 16
    for (int k = 0; k < 16; ++k) {
        f32x4 o4;
        o4.x = fmaf(y[k], w4.x, b4.x);
        o4.y = fmaf(y[k], w4.y, b4.y);
        o4.z = fmaf(y[k], w4.z, b4.z);
        o4.w = fmaf(y[k], w4.w, b4.w);
        __builtin_nontemporal_store(o4, o + base + k * stride);
    }
}

extern "C" void kernel_launch(void* const* d_in, const int* in_sizes, int n_in,
                              void* d_out, int out_size, void* d_ws, size_t ws_size,
                              hipStream_t stream) {
    const int*   ids  = (const int*)d_in[0];
    const float* W    = (const float*)d_in[1];
    const float* bias = (const float*)d_in[2];
    float* out = (float*)d_out;
    unsigned char* ws8 = (unsigned char*)d_ws;

    prep_kernel<<<512, 256, 0, stream>>>(ids, ws8);
    conv_kernel<<<NBAT * 32, 256, 0, stream>>>(ids, ws8);
    // Duration probe: identical idempotent write launched twice.
    write_kernel<<<2048, 256, 0, stream>>>(ws8, W, bias, out);
    write_kernel<<<2048, 256, 0, stream>>>(ws8, W, bias, out);
}

// Round 17
// 38.337 us; speedup vs baseline: 1.9379x; 1.9379x over previous
//
#include <hip/hip_runtime.h>
#include <hip/hip_bf16.h>
#include <math.h>

// B=16, S=8192, D=256. out[b,s,d] = y[b,s]*W[d] + bias[d],
// y = lowpass(x) keep |f|<2048, x = ids/255.
// Parity split: y[2i]   = 0.5*x_e[i] + sum_j Kp[j]*x_o[(i-1-j) mod 4096]
//               y[2i+1] = 0.5*x_o[i] + sum_j Kp[j]*x_e[(i-j)   mod 4096]
// Kp[j] = (-1)^j * cot(pi*(2j+1)/8192)/8192.
// conv_kernel (512 blocks): MFMA FIR -> ys[b][s] (512 KB ws, L2-resident).
// write_kernel (LOW-OCCUPANCY fill-mimic): 1024 blocks (4/CU), 8 iters x
// 4 independent plain float4 stores/thread, sweeping 16 MiB windows; y via
// readfirstlane scalar load so the VMEM pipe carries ONLY stores.
// R16 probe measured: write = 34.8us @2048 blocks (3.85 TB/s) vs fill 6.9 TB/s
// at ~3 blocks/CU -> stream-count/occupancy is the last untested variable.

#define SEQ    8192
#define HSEQ   4096
#define DIM    256
#define NBAT   16
#define RROW   8224                     // unrolled circular reversed row (shorts)
#define APN    (128*512)                // Apack shorts: 128 j-blocks x 64 lanes x 8
#define AP_OFF 0
#define RO_OFF (APN*2)                  // 131072 B
#define RE_OFF (RO_OFF + NBAT*RROW*2)   // 394240 B
#define YS_OFF (RE_OFF + NBAT*RROW*2)   // 657408 B; ys = 16*8192 f32 = 512 KB

typedef __attribute__((ext_vector_type(8))) short short8v;
typedef __attribute__((ext_vector_type(4))) float f32x4;

__device__ __forceinline__ short bfbits(float f) {
    __hip_bfloat16 h = __float2bfloat16(f);
    return *(short*)&h;
}

__global__ __launch_bounds__(256)
void prep_kernel(const int* __restrict__ ids, unsigned char* __restrict__ ws8) {
    short* Ap = (short*)(ws8 + AP_OFF);
    short* Ro = (short*)(ws8 + RO_OFF);
    short* Re = (short*)(ws8 + RE_OFF);
    const int idx = blockIdx.x * 256 + threadIdx.x;
    const int n   = gridDim.x * 256;

    // A fragments in lane order: Ap[jb*512 + l*8 + e] = Ktil[(32jb + oc + 8koff + e) mod 4096]
    for (int i = idx; i < APN; i += n) {
        int jb = i >> 9, r = i & 511, l = r >> 3, e = r & 7;
        int oc = l & 15, koff = l >> 4;
        int j = (32 * jb + oc + 8 * koff + e) & (HSEQ - 1);
        double ang = M_PI * (2.0 * j + 1.0) / 8192.0;
        double v = (cos(ang) / sin(ang)) / (8192.0 * 255.0);
        if (j & 1) v = -v;
        Ap[i] = bfbits((float)v);
    }
    // Reversed parity rows (raw id units, exact bf16), periodic unrolled:
    //  Ro[b][u] = ids[b][2*((4095-u)&4095)+1], Re[b][u] = ids[b][2*((4096-u)&4095)]
    for (int i = idx; i < NBAT * RROW; i += n) {
        int b = i / RROW, u = i - b * RROW;
        const int* row = ids + b * SEQ;
        int mo = (4095 - u) & (HSEQ - 1);
        int me = (4096 - u) & (HSEQ - 1);
        Ro[i] = bfbits((float)row[2 * mo + 1]);
        Re[i] = bfbits((float)row[2 * me]);
    }
}

__global__ __launch_bounds__(256)
void conv_kernel(const int* __restrict__ ids,
                 unsigned char* __restrict__ ws8) {
    __shared__ f32x4 red[4][64];

    const int bid = blockIdx.x;
    const int chunk = bid & 31;          // 32 chunks of 256 samples per row
    const int b  = bid >> 5;
    const int s0 = chunk << 8;
    const int i0 = s0 >> 1;              // packed-output base per parity
    const int t = threadIdx.x, w = t >> 6, l = t & 63;
    const int oc = l & 15, koff = l >> 4;
    const int P = oc >> 3, g = oc & 7;   // column = (parity, group)

    // A: contiguous 1KB per wave per iter (pre-packed lane order)
    const short* Apw = (const short*)(ws8 + AP_OFF) + ((w * 32) << 9) + l * 8;
    // B: one Rev row per lane; same base offset for both parities
    const short* Rp = (const short*)(ws8 + (P ? RE_OFF : RO_OFF)) + b * RROW
                      + (HSEQ - i0 - 16 * g) + 8 * koff + (w << 10);

    f32x4 acc = {0.f, 0.f, 0.f, 0.f};
    #pragma unroll 4
    for (int c = 0; c < 32; ++c) {
        short8v a  = *(const short8v*)(Apw + (c << 9));
        short8v bv = *(const short8v*)(Rp + (c << 5));
        acc = __builtin_amdgcn_mfma_f32_16x16x32_bf16(a, bv, acc, 0, 0, 0);
    }
    red[w][l] = acc;
    __syncthreads();

    // One output per thread. C layout (m89): col = lane&15, row = (lane>>4)*4+q.
    // Value C[o][g2] -> local s = 2*(16*(g2&7) + o) + (g2>>3).
    {
        const int g2 = t >> 4, o = t & 15;
        float s = 0.f;
        #pragma unroll
        for (int k = 0; k < 4; ++k) s += red[k][(o >> 2) * 16 + g2][o & 3];
        const int ls = 2 * (16 * (g2 & 7) + o) + (g2 >> 3);
        s += (float)ids[b * SEQ + s0 + ls] * (0.5f / 255.0f);
        ((float*)(ws8 + YS_OFF))[b * SEQ + s0 + ls] = s;
    }
}

__global__ __launch_bounds__(256)
void write_kernel(const unsigned char* __restrict__ ws8,
                  const float* __restrict__ W,
                  const float* __restrict__ bias,
                  float* __restrict__ out) {
    const float* ys = (const float*)(ws8 + YS_OFF);
    const int t = threadIdx.x;
    const int d = (t & 63) << 2;               // f4-idx % 64 == t % 64
    const float4 w4 = *(const float4*)(W + d);
    const float4 b4 = *(const float4*)(bias + d);

    // 8 iterations x 4 sub-streams x 1024 blocks x 256 threads = 8,388,608 f4.
    // f4 idx = it*1048576 + j*262144 + bid*1024 + (t>>6)*256 ... no: keep wave
    // 1KB contiguous: idx = it*1048576 + bid*1024 + j*256 + t.
    f32x4* o = (f32x4*)out;
    const int base0 = blockIdx.x * 1024 + t;
    #pragma unroll 1
    for (int it = 0; it < 8; ++it) {
        const int base = it * 1048576 + base0;
        #pragma unroll
        for (int j = 0; j < 4; ++j) {
            const int idx = base + j * 256;
            // wave-uniform ys index: (idx>>6) constant across lanes (t<64 span)
            const float y = ys[__builtin_amdgcn_readfirstlane(idx >> 6)];
            f32x4 o4;
            o4.x = fmaf(y, w4.x, b4.x);
            o4.y = fmaf(y, w4.y, b4.y);
            o4.z = fmaf(y, w4.z, b4.z);
            o4.w = fmaf(y, w4.w, b4.w);
            o[idx] = o4;                       // plain store, fill-mimic
        }
    }
}

extern "C" void kernel_launch(void* const* d_in, const int* in_sizes, int n_in,
                              void* d_out, int out_size, void* d_ws, size_t ws_size,
                              hipStream_t stream) {
    const int*   ids  = (const int*)d_in[0];
    const float* W    = (const float*)d_in[1];
    const float* bias = (const float*)d_in[2];
    float* out = (float*)d_out;
    unsigned char* ws8 = (unsigned char*)d_ws;

    prep_kernel<<<512, 256, 0, stream>>>(ids, ws8);
    conv_kernel<<<NBAT * 32, 256, 0, stream>>>(ids, ws8);
    write_kernel<<<1024, 256, 0, stream>>>(ws8, W, bias, out);
}